// Round 8
// baseline (1263.268 us; speedup 1.0000x reference)
//
#include <hip/hip_runtime.h>

// HyperNetSIR: x(N,3) f32, H(E,N) f32 0/1 mask (density 0.002), beta(N), gamma(N), steps(int)
// out: (steps, N, 3) f32 trajectory.
//
// v8 strategy — SCATTER formulation, one barrier per step:
//  Rounds 2-7 showed step time (~10us) is invariant to barrier topology,
//  block count, wave count => the cost is the LENGTH of the serial
//  coherent-hop chain (~1.5us per cross-XCD round trip), not its width.
//  Old chain/step: read I -> store y -> pub -> detect -> read y -> store I
//  -> pub -> detect  (~6 hops). New chain/step (~3 hops): each node owner
//  gathers y for its edges, updates S/I/R in registers, and atomicAdds its
//  new I directly into y_next[e] for its ~10 incident edges. The shared I
//  array and the whole edge phase disappear; one barrier per step.
//  - fixed-point accumulation: ivq = rint(I * 2^24) int atomicAdd (HW atomic,
//    device scope, no fp-atomic lowering risk). y[e] <= 96 -> max 96*2^24
//    fits int32. Gather converts back with one *2^-24.
//  - y slots padded to one 64B line (YPAD=16 ints): <=96 RMWs/line/step
//    serialize per-line only (~30cy each), lines independent.
//  - triple-buffered y: step t reads buf[cur], adds into buf[nxt], zeroes
//    buf[zer] (for t+1's adds). All races separated by the single barrier.
//  - barrier: v4's RMW-counter (8 spread lines) — best measured primitive
//    (flag-store version regressed: 128x64-lane polling saturates the
//    coherent read path).
//  build_adjacency: v6 two-pass (time-invariant across 4 variants; leave it).

#define EDGE_CAP 96   // max nodes per edge (mean 40, sigma 6.3)
#define NODE_CAP 32   // max edges per node (mean 10, sigma 3.2)
#define NIDX_REG 16   // node-adjacency indices held in registers (P(cnt>16) ~ 3%)
#define COOP_BLOCKS 128
#define COOP_THREADS 1024
#define BAR_LINES 8
#define BAR_STRIDE 128                    // u32s -> 512B between counter lines
#define BAR_UINTS (BAR_LINES * BAR_STRIDE)
#define YPAD 16                           // ints per y slot = one 64B line
#define ISCALE 16777216.0f                // 2^24
#define INV_ISCALE 5.9604644775390625e-8f // 2^-24

typedef unsigned int uint4_ev __attribute__((ext_vector_type(4)));

__global__ void zero_ws_kernel(int* edge_cnt, int* node_cnt, unsigned* bar,
                               int* ybufs, int n_edges, int n_nodes, int ytot) {
    int i = blockIdx.x * blockDim.x + threadIdx.x;
    if (i < BAR_UINTS) bar[i] = 0u;
    if (i < n_edges) edge_cnt[i] = 0;
    if (i < n_nodes) node_cnt[i] = 0;
    if (i < ytot) ybufs[i] = 0;
}

// One block (256 threads) per edge row (v6, unchanged).
// Pass A: stream row with 16B loads, per-wave ballot masks of nonzero quads.
// Pass B: revisit only nonzero quads (L2-hot) for LDS-atomic compaction.
__global__ void build_adjacency_kernel(const float* __restrict__ H,
                                       int* __restrict__ edge_cnt,
                                       int* __restrict__ edge_nodes,
                                       int* __restrict__ node_cnt,
                                       int* __restrict__ node_edges,
                                       int n_nodes) {
    __shared__ int cnt;
    __shared__ int cols[EDGE_CAP];
    __shared__ unsigned long long qmask[128];   // supports n_nodes <= 32768
    const int e  = blockIdx.x;
    const int tx = threadIdx.x;
    if (tx == 0) cnt = 0;
    const float* row = H + (size_t)e * n_nodes;
    const uint4_ev* row4 = (const uint4_ev*)row;
    const int n4 = n_nodes >> 2;
    const int niter = (n4 + 255) >> 8;

    for (int i = 0; i < niter; ++i) {
        int q = (i << 8) + tx;
        uint4_ev v = {0u, 0u, 0u, 0u};
        if (q < n4) v = row4[q];
        unsigned long long m = __ballot((v.x | v.y | v.z | v.w) != 0u);
        if ((tx & 63) == 0) qmask[(i << 2) + (tx >> 6)] = m;
    }
    __syncthreads();

    const int nslots = niter << 2;
    for (int sIdx = tx; sIdx < nslots; sIdx += blockDim.x) {
        unsigned long long m = qmask[sIdx];
        int qbase = ((sIdx >> 2) << 8) + ((sIdx & 3) << 6);
        while (m) {
            int lane = __builtin_ctzll(m); m &= m - 1;
            int q = qbase + lane;
            uint4_ev v = row4[q];               // L2 hit
            int cbase = q << 2;
            if (v.x) { int p = atomicAdd(&cnt, 1); if (p < EDGE_CAP) cols[p] = cbase; }
            if (v.y) { int p = atomicAdd(&cnt, 1); if (p < EDGE_CAP) cols[p] = cbase + 1; }
            if (v.z) { int p = atomicAdd(&cnt, 1); if (p < EDGE_CAP) cols[p] = cbase + 2; }
            if (v.w) { int p = atomicAdd(&cnt, 1); if (p < EDGE_CAP) cols[p] = cbase + 3; }
        }
    }
    if (tx == 0) {   // tail (n_nodes not multiple of 4)
        for (int c = n4 << 2; c < n_nodes; ++c)
            if (row[c] != 0.0f) { int p = atomicAdd(&cnt, 1); if (p < EDGE_CAP) cols[p] = c; }
    }
    __syncthreads();

    int cn = min(cnt, EDGE_CAP);
    if (tx == 0) edge_cnt[e] = cn;
    for (int i = tx; i < cn; i += blockDim.x) {
        int c = cols[i];
        edge_nodes[e * EDGE_CAP + i] = c;
        int q = atomicAdd(&node_cnt[c], 1);     // device-scope, batched
        if (q < NODE_CAP) node_edges[c * NODE_CAP + q] = e;
    }
}

// Coherent (cross-XCD) access helpers: sc-flagged, bypass non-coherent L1/L2.
__device__ __forceinline__ int coh_loadi(const int* p) {
    return __hip_atomic_load(p, __ATOMIC_RELAXED, __HIP_MEMORY_SCOPE_AGENT);
}
__device__ __forceinline__ void coh_storei(int* p, int v) {
    __hip_atomic_store(p, v, __ATOMIC_RELAXED, __HIP_MEMORY_SCOPE_AGENT);
}

// Flat 2-hop RMW-counter barrier (v4, best measured). Arrive: drain this
// wave's memory ops (vmcnt 0 covers the atomicAdd scatter), block-sync,
// thread0 RMWs one of 8 spread counter lines. Wait: thread0 sums the 8
// lines until target. Monotonic counters + relaxed loads: stale reads only
// delay, never false-positive.
__device__ __forceinline__ void bar_arrive(unsigned* bar) {
    asm volatile("s_waitcnt vmcnt(0)" ::: "memory");
    __syncthreads();
    if (threadIdx.x == 0)
        __hip_atomic_fetch_add(&bar[(blockIdx.x & (BAR_LINES - 1)) * BAR_STRIDE], 1u,
                               __ATOMIC_RELAXED, __HIP_MEMORY_SCOPE_AGENT);
}
__device__ __forceinline__ void bar_wait(unsigned* bar, unsigned target) {
    if (threadIdx.x == 0) {
        for (;;) {
            unsigned sum = 0;
            #pragma unroll
            for (int i = 0; i < BAR_LINES; ++i)
                sum += __hip_atomic_load(&bar[i * BAR_STRIDE], __ATOMIC_RELAXED,
                                         __HIP_MEMORY_SCOPE_AGENT);
            if (sum >= target) break;
            __builtin_amdgcn_s_sleep(1);
        }
    }
    __syncthreads();
    asm volatile("" ::: "memory");
}

// All SIR steps in one persistent kernel, one barrier per step.
// Requires: n_nodes <= node_chunk*gridDim with node_chunk <= blockDim.
__global__ __launch_bounds__(COOP_THREADS) void sir_steps_kernel(
        const float* __restrict__ x,
        const int* __restrict__ node_cnt, const int* __restrict__ node_edges,
        const float* __restrict__ beta, const float* __restrict__ gamma,
        int* __restrict__ yb0, int* __restrict__ yb1, int* __restrict__ yb2,
        float* __restrict__ out,
        int n_nodes, int n_edges, int steps, unsigned* bar) {
    const int b  = blockIdx.x;
    const int tx = threadIdx.x;

    const int node_chunk = (n_nodes + gridDim.x - 1) / gridDim.x;   // 157
    const int edge_chunk = (n_edges + gridDim.x - 1) / gridDim.x;   // 40
    const int n = b * node_chunk + tx;
    const bool own = (tx < node_chunk) && (n < n_nodes);

    // ---- per-node adjacency into registers (dummy = slot n_edges, stays 0) ----
    int ncnt = 0;
    const int* ne = node_edges;
    float bet = 0.0f, gam = 0.0f;
    if (own) { ncnt = min(node_cnt[n], NODE_CAP); ne = node_edges + n * NODE_CAP;
               bet = beta[n]; gam = gamma[n]; }
    int nidx[NIDX_REG];
    #pragma unroll
    for (int i = 0; i < NIDX_REG; ++i)
        nidx[i] = (own && i < ncnt) ? ne[i] : n_edges;

    // ---- init: state to regs, traj[0], scatter I0 into yb1 ----
    float s = 0.0f, iv = 0.0f, r = 0.0f;
    if (own) {
        s = x[n * 3 + 0]; iv = x[n * 3 + 1]; r = x[n * 3 + 2];
        out[n * 3 + 0] = s; out[n * 3 + 1] = iv; out[n * 3 + 2] = r;
        int ivq = (int)rintf(iv * ISCALE);
        #pragma unroll
        for (int i = 0; i < NIDX_REG; ++i)
            if (i < ncnt) atomicAdd(&yb1[nidx[i] * YPAD], ivq);
        for (int i = NIDX_REG; i < ncnt; ++i) atomicAdd(&yb1[ne[i] * YPAD], ivq);
    }
    unsigned bars = 0;
    bar_arrive(bar); bars += gridDim.x; bar_wait(bar, bars);

    // rotation: step t reads cur, adds into nxt, zeroes zer (= nxt at t+1).
    int* cur = yb1; int* nxt = yb2; int* zer = yb0;
    for (int t = 1; t < steps; ++t) {
        if (own) {
            // gather y (independent coherent loads; dummies read exact 0)
            int tvq[NIDX_REG];
            #pragma unroll
            for (int i = 0; i < NIDX_REG; ++i) tvq[i] = coh_loadi(&cur[nidx[i] * YPAD]);
            float z = 0.0f;
            #pragma unroll
            for (int i = 0; i < NIDX_REG; ++i) z += (float)tvq[i];
            for (int i = NIDX_REG; i < ncnt; ++i)
                z += (float)coh_loadi(&cur[ne[i] * YPAD]);   // rare tail
            z *= INV_ISCALE;
            // SIR update in registers
            float nc = bet * s * z;
            float nr = gam * iv;
            float s2 = fmaxf(s - nc, 0.0f);
            float i2 = fmaxf(iv + nc - nr, 0.0f);
            float r2 = fmaxf(r + nr, 0.0f);
            float inv = 1.0f / (s2 + i2 + r2);
            s = s2 * inv; iv = i2 * inv; r = r2 * inv;
            // scatter new I into next step's y (fire-and-forget HW RMWs)
            if (t + 1 < steps) {
                int ivq = (int)rintf(iv * ISCALE);
                #pragma unroll
                for (int i = 0; i < NIDX_REG; ++i)
                    if (i < ncnt) atomicAdd(&nxt[nidx[i] * YPAD], ivq);
                for (int i = NIDX_REG; i < ncnt; ++i) atomicAdd(&nxt[ne[i] * YPAD], ivq);
            }
        }
        // zero zer (receives adds at t+1; everyone's reads of it ended at t-1)
        if (t + 2 < steps) {
            int base = b * edge_chunk;
            for (int zz = tx; zz < edge_chunk; zz += blockDim.x) {
                int ei = base + zz;
                if (ei < n_edges) coh_storei(&zer[ei * YPAD], 0);
            }
        }
        bar_arrive(bar); bars += gridDim.x;
        if (own) {   // traj store (host-consumed only) overlaps the wait
            float* ot = out + (size_t)t * n_nodes * 3 + (size_t)n * 3;
            ot[0] = s; ot[1] = iv; ot[2] = r;
        }
        if (t + 1 < steps) bar_wait(bar, bars);
        int* tmp = cur; cur = nxt; nxt = zer; zer = tmp;
    }
}

extern "C" void kernel_launch(void* const* d_in, const int* in_sizes, int n_in,
                              void* d_out, int out_size, void* d_ws, size_t ws_size,
                              hipStream_t stream) {
    const float* x     = (const float*)d_in[0];
    const float* H     = (const float*)d_in[1];
    const float* beta  = (const float*)d_in[2];
    const float* gamma = (const float*)d_in[3];
    float* out = (float*)d_out;

    const int n_nodes = in_sizes[0] / 3;                 // 20000
    const int n_edges = in_sizes[1] / n_nodes;           // 5000
    const int steps   = out_size / in_sizes[0];          // 50

    const int yslots = (n_edges + 1) * YPAD;             // +1 dummy slot
    const int ytot   = 3 * yslots;

    // workspace carve-up (ints/floats are both 4B)
    char* ws = (char*)d_ws;
    unsigned* bar     = (unsigned*)ws;                    ws += (size_t)BAR_UINTS * 4;
    int*   edge_cnt   = (int*)ws;                         ws += (size_t)n_edges * 4;
    int*   node_cnt   = (int*)ws;                         ws += (size_t)n_nodes * 4;
    int*   edge_nodes = (int*)ws;                         ws += (size_t)n_edges * EDGE_CAP * 4;
    int*   node_edges = (int*)ws;                         ws += (size_t)n_nodes * NODE_CAP * 4;
    int*   ybufs      = (int*)ws;                         ws += (size_t)ytot * 4;
    int*   yb0 = ybufs;
    int*   yb1 = ybufs + yslots;
    int*   yb2 = ybufs + 2 * yslots;

    // 1. zero counters + barrier + y buffers (ws is poisoned 0xAA each call)
    {
        int mx = max(ytot, max(n_edges, max(n_nodes, (int)BAR_UINTS)));
        zero_ws_kernel<<<(mx + 255) / 256, 256, 0, stream>>>(edge_cnt, node_cnt, bar,
                                                             ybufs, n_edges, n_nodes, ytot);
    }
    // 2. extract sparsity of H (the one unavoidable 400MB scan)
    build_adjacency_kernel<<<n_edges, 256, 0, stream>>>(H, edge_cnt, edge_nodes,
                                                        node_cnt, node_edges, n_nodes);
    // 3. all SIR steps in one persistent kernel, ONE barrier per step
    sir_steps_kernel<<<COOP_BLOCKS, COOP_THREADS, 0, stream>>>(
        x, node_cnt, node_edges, beta, gamma,
        yb0, yb1, yb2, out, n_nodes, n_edges, steps, bar);
}